// Round 2
// baseline (472.250 us; speedup 1.0000x reference)
//
#include <hip/hip_runtime.h>
#include <cstdint>
#include <cstddef>

// ---------------------------------------------------------------------------
// NN_each_LN_exp: 33x33 SAME convs on 32x32 maps = dense 1024x1024 linear
// operators -> f16 MFMA GEMMs with fused epilogues. Row layout r = n*4+k.
// R17: all big GEMMs ported to the 256^2 / 8-wave / 8-phase counted-vmcnt
// schedule (T2+T3+T4+T5). Depth dataflow reverted to materialized P (R15
// numerics, bit-identical). P buffers alias dead notmF/eachF regions.
// Schedule (per K-tile, quadrants (0,0),(1,0),(1,1),(0,1)):
//   P1: read A0+B0, stage A0(t+1)->free buf
//   P2: read A1 (reuse B0 regs), stage B1(t+1)->free buf
//   P3: read B1 (reuse A1 regs), stage B0(t+2)->live buf (B0 reads done @P1)
//   P4: re-read A0 (reuse B1),   stage A1(t+2)->live buf (A1 reads done @P2)
//   vmcnt(4) once per tile (vmcnt(0) at t=14: tail predication shifts count)
// Session ledger: 128^2 m97-structure ceiling reached (R4..R15, ~550-900 TF);
// NC*s in-register regressed (R16: lengthened ds_read->MFMA critical path).
// ---------------------------------------------------------------------------

typedef _Float16 f16;
typedef __attribute__((ext_vector_type(8))) _Float16 f16x8;
typedef __attribute__((ext_vector_type(4))) float f32x4;

#define NB   4096
#define PIX  1024
#define MR   (NB * 4)

__device__ __forceinline__ void gld_lds16(const void* g, void* l) {
    __builtin_amdgcn_global_load_lds(
        (const __attribute__((address_space(1))) void*)g,
        (__attribute__((address_space(3))) void*)l, 16, 0, 0);
}

// Merged builds: [0,4096) conv mats, [4096,4608) W1 pad, [4608,5632) board
__global__ void build_all(const float* __restrict__ we, const float* __restrict__ wn,
                          const float* __restrict__ wn2, const float* __restrict__ wem,
                          const float* __restrict__ W1, const int* __restrict__ dots,
                          f16* __restrict__ Me, f16* __restrict__ Mn,
                          f16* __restrict__ Mn2, f16* __restrict__ Mem,
                          f16* __restrict__ W1b, unsigned char* __restrict__ board) {
    __shared__ unsigned char tile[64][68];
    int bi = blockIdx.x, t = threadIdx.x;
    if (bi < 4096) {
        int idx = bi * 256 + t;
        int o = idx >> 10, in = idx & 1023;
        int i = o >> 5, j = o & 31, a = in >> 5, b = in & 31;
        int u = a - i + 16, v = b - j + 16;
        bool ok = (u >= 0) && (u < 33) && (v >= 0) && (v < 33);
        int w = u * 33 + v;
        float ve = 0.f, vn = 0.f, vn2 = 0.f, vem = 0.f;
        if (ok) { ve = we[w]; vn = wn[w]; vn2 = wn2[w]; vem = wem[w]; }
        Me[idx]  = (f16)ve;
        Mn[idx]  = (f16)vn;
        Mn2[idx] = (f16)vn2;
        Mem[idx] = (f16)vem;
    } else if (bi < 4608) {
        int idx = (bi - 4096) * 256 + t;
        int j = idx >> 10, i = idx & 1023;
        W1b[idx] = (f16)(j < 100 ? W1[j * 1024 + i] : 0.f);
    } else {
        int bb = bi - 4608;
        int bp = bb & 15, bn = bb >> 4;
        int p0 = bp * 64, n0 = bn * 64;
        int ln = t & 63, lp = t >> 6;
#pragma unroll
        for (int j = 0; j < 16; j++) {
            int p = lp * 16 + j;
            tile[p][ln] = (unsigned char)dots[(size_t)(p0 + p) * 4096 + n0 + ln];
        }
        __syncthreads();
#pragma unroll
        for (int j = 0; j < 16; j++) {
            int n = lp * 16 + j;
            board[(size_t)(n0 + n) * 1024 + p0 + ln] = tile[ln][n];
        }
    }
}

// Expand board -> f16 mask matrices (pure-BW kernel, once).
__global__ void expand_masks(const unsigned char* __restrict__ board,
                             f16* __restrict__ eachF, f16* __restrict__ notmF,
                             f16* __restrict__ emptyF) {
    int bi = blockIdx.x, t = threadIdx.x;
    if (bi < 8192) {
        int idx = bi * 256 + t;
        int r = idx >> 7, w0 = (idx & 127) << 3;
        int n = r >> 2, k1 = (r & 3) + 1;
        uint64_t bb = *(const uint64_t*)(board + (size_t)n * 1024 + w0);
        f16x8 e, m;
#pragma unroll
        for (int j = 0; j < 8; j++) {
            int bj = (int)((bb >> (8 * j)) & 0xff);
            e[j] = (bj == k1) ? (f16)1.f : (f16)0.f;
            m[j] = (bj != 0 && bj != k1) ? (f16)1.f : (f16)0.f;
        }
        *(f16x8*)(eachF + (size_t)idx * 8) = e;
        *(f16x8*)(notmF + (size_t)idx * 8) = m;
    } else {
        int idx = (bi - 8192) * 256 + t;
        int n = idx >> 7, w0 = (idx & 127) << 3;
        uint64_t bb = *(const uint64_t*)(board + (size_t)n * 1024 + w0);
        f16x8 e;
#pragma unroll
        for (int j = 0; j < 8; j++)
            e[j] = (((bb >> (8 * j)) & 0xff) == 0) ? (f16)1.f : (f16)0.f;
        *(f16x8*)(emptyF + (size_t)idx * 8) = e;
    }
}

// ---------------------------------------------------------------------------
// 256x256-tile 8-phase GEMM, 512 threads (8 waves as 2x4), BK=64, LDS 128KB
// (2 buf x {A0,A1,B0,B1} x 16KB). C = A(rows) . B(rows)^T, K=1024, NT=16.
// MODE: 0 plain f16 store (outB, ldo)
//       2 stage1 mk_sa: L0 = asel + En - NCsel; Lsel, Pout = NC*sigmoid
//       3 depth:        Lnew = Lsel + En + asel; Lsel, Pout = NC*sigmoid
//       4 depth final:  outB[no] = sigmoid (feat)
// ---------------------------------------------------------------------------
#define READA(MH) \
    _Pragma("unroll") for (int i = 0; i < 4; i++) \
    _Pragma("unroll") for (int kk = 0; kk < 2; kk++) { \
        int rr = wm * 64 + i * 16 + lr; \
        aF[i][kk] = *(const f16x8*)(smem + bufo + (MH) * 16384 + rr * 128 + \
                                    (((kk * 4 + lq) ^ (rr & 7)) * 16)); \
    }

#define READB(NH) \
    _Pragma("unroll") for (int j = 0; j < 2; j++) \
    _Pragma("unroll") for (int kk = 0; kk < 2; kk++) { \
        int cc = wn * 32 + j * 16 + lr; \
        bF[j][kk] = *(const f16x8*)(smem + bufo + 32768 + (NH) * 16384 + cc * 128 + \
                                    (((kk * 4 + lq) ^ (cc & 7)) * 16)); \
    }

#define MFMAQ(MH, NH) \
    _Pragma("unroll") for (int i = 0; i < 4; i++) \
    _Pragma("unroll") for (int j = 0; j < 2; j++) \
    _Pragma("unroll") for (int kk = 0; kk < 2; kk++) \
        acc[MH][NH][i][j] = __builtin_amdgcn_mfma_f32_16x16x32_f16( \
            aF[i][kk], bF[j][kk], acc[MH][NH][i][j], 0, 0, 0);

#define STAGEA(TT, H) { \
    int bo = ((TT) & 1) * 65536 + (H) * 16384; \
    _Pragma("unroll") for (int s = 0; s < 2; s++) { \
        int c = s * 512 + tid; int row = c >> 3; int gc = (c & 7) ^ (row & 7); \
        gld_lds16(Ag + (size_t)(rtile + (H) * 128 + row) * 1024 + (TT) * 64 + gc * 8, \
                  smem + bo + c * 16); } }

#define STAGEB(TT, H) { \
    int bo = ((TT) & 1) * 65536 + 32768 + (H) * 16384; \
    _Pragma("unroll") for (int s = 0; s < 2; s++) { \
        int c = s * 512 + tid; int row = c >> 3; int gc = (c & 7) ^ (row & 7); \
        gld_lds16(Bg + (size_t)(otile + (H) * 128 + row) * 1024 + (TT) * 64 + gc * 8, \
                  smem + bo + c * 16); } }

template <int MODE>
__device__ __forceinline__ void gemm8_run(
    int bjob, int nyt8, char* smem,
    const f16* __restrict__ Ag, const f16* __restrict__ Bg,
    const unsigned char* __restrict__ board, const f16* __restrict__ En,
    const f16* __restrict__ NC, f16* __restrict__ Lsel,
    f16* __restrict__ Pout, f16* __restrict__ outB, int ldo) {
    const int tid = threadIdx.x;
    const int wv = tid >> 6, ln = tid & 63;
    const int wm = wv >> 2, wn = wv & 3;          // 2x4 wave grid
    const int lr = ln & 15, lq = ln >> 4;

    int xcd = bjob & 7, idx = bjob >> 3;
    int bx = idx & 3;
    int by = xcd * nyt8 + (idx >> 2);
    const int rtile = by * 256, otile = bx * 256;

    const f32x4 fz = {0.f, 0.f, 0.f, 0.f};
    f32x4 acc[2][2][4][2];
#pragma unroll
    for (int mh = 0; mh < 2; mh++)
#pragma unroll
        for (int nh = 0; nh < 2; nh++)
#pragma unroll
            for (int i = 0; i < 4; i++)
#pragma unroll
                for (int j = 0; j < 2; j++) acc[mh][nh][i][j] = fz;

    f16x8 aF[4][2], bF[2][2];

    // prologue: tile0 full + B0(1), A1(1); tile0 guaranteed by vmcnt(4)
    STAGEA(0, 0) STAGEB(0, 0) STAGEA(0, 1) STAGEB(0, 1)
    STAGEB(1, 0) STAGEA(1, 1)
    asm volatile("s_waitcnt vmcnt(4)" ::: "memory");
    __builtin_amdgcn_s_barrier();

    for (int t = 0; t < 16; t++) {
        const int bufo = (t & 1) * 65536;
        // ---- P1: quadrant (0,0) ----
        READA(0) READB(0)
        if (t < 15) STAGEA(t + 1, 0)
        __builtin_amdgcn_s_barrier();
        asm volatile("s_waitcnt lgkmcnt(0)" ::: "memory");
        __builtin_amdgcn_s_setprio(1);
        MFMAQ(0, 0)
        __builtin_amdgcn_s_setprio(0);
        __builtin_amdgcn_s_barrier();
        // ---- P2: quadrant (1,0), reuse B0 regs ----
        READA(1)
        if (t < 15) STAGEB(t + 1, 1)
        __builtin_amdgcn_s_barrier();
        asm volatile("s_waitcnt lgkmcnt(0)" ::: "memory");
        __builtin_amdgcn_s_setprio(1);
        MFMAQ(1, 0)
        __builtin_amdgcn_s_setprio(0);
        __builtin_amdgcn_s_barrier();
        // ---- P3: quadrant (1,1), reuse A1 regs; B0(t) reads done @P1 ----
        READB(1)
        if (t < 14) STAGEB(t + 2, 0)
        __builtin_amdgcn_s_barrier();
        asm volatile("s_waitcnt lgkmcnt(0)" ::: "memory");
        __builtin_amdgcn_s_setprio(1);
        MFMAQ(1, 1)
        __builtin_amdgcn_s_setprio(0);
        __builtin_amdgcn_s_barrier();
        // ---- P4: quadrant (0,1), re-read A0, reuse B1; A1(t) reads done @P2 ----
        READA(0)
        if (t < 14) STAGEA(t + 2, 1)
        __builtin_amdgcn_s_barrier();
        asm volatile("s_waitcnt lgkmcnt(0)" ::: "memory");
        __builtin_amdgcn_s_setprio(1);
        MFMAQ(0, 1)
        __builtin_amdgcn_s_setprio(0);
        if (t < 14) { asm volatile("s_waitcnt vmcnt(4)" ::: "memory"); }
        else        { asm volatile("s_waitcnt vmcnt(0)" ::: "memory"); }
        __builtin_amdgcn_s_barrier();
    }

    // ---- epilogue ----
#pragma unroll
    for (int mh = 0; mh < 2; mh++)
#pragma unroll
        for (int nh = 0; nh < 2; nh++)
#pragma unroll
            for (int i = 0; i < 4; i++)
#pragma unroll
                for (int j = 0; j < 2; j++) {
                    f32x4 a = acc[mh][nh][i][j];
                    int rbase = rtile + mh * 128 + wm * 64 + i * 16 + lq * 4;
                    int o = otile + nh * 128 + wn * 32 + j * 16 + lr;
                    if constexpr (MODE == 0) {
#pragma unroll
                        for (int v = 0; v < 4; v++)
                            outB[(size_t)(rbase + v) * ldo + o] = (f16)a[v];
                    } else if constexpr (MODE == 2) {
                        int n = rbase >> 2;
                        size_t no = (size_t)n * PIX + o;
                        int c = board[no];
                        size_t r0 = (size_t)rbase * PIX + o;
                        f16 nc0 = NC[r0], nc1 = NC[r0 + PIX];
                        f16 nc2 = NC[r0 + 2 * PIX], nc3 = NC[r0 + 3 * PIX];
                        float L = 0.f;
                        if (c > 0) {
                            float asel = (c == 1) ? a[0] : (c == 2) ? a[1]
                                       : (c == 3) ? a[2] : a[3];
                            float ncsel = (float)((c == 1) ? nc0 : (c == 2) ? nc1
                                                : (c == 3) ? nc2 : nc3);
                            L = asel + (float)En[no] - ncsel;
                        }
                        Lsel[no] = (f16)L;
                        f16 s = (f16)(1.f / (1.f + __expf(-L)));
                        Pout[r0]           = nc0 * s;
                        Pout[r0 + PIX]     = nc1 * s;
                        Pout[r0 + 2 * PIX] = nc2 * s;
                        Pout[r0 + 3 * PIX] = nc3 * s;
                    } else {
                        int n = rbase >> 2;
                        size_t no = (size_t)n * PIX + o;
                        int c = board[no];
                        float Lnew = 0.f;
                        if (c > 0) {
                            float asel = (c == 1) ? a[0] : (c == 2) ? a[1]
                                       : (c == 3) ? a[2] : a[3];
                            Lnew = (float)Lsel[no] + (float)En[no] + asel;
                        }
                        f16 s = (f16)(1.f / (1.f + __expf(-Lnew)));
                        if constexpr (MODE == 4) {
                            outB[no] = s;
                        } else {
                            Lsel[no] = (f16)Lnew;
                            size_t r0 = (size_t)rbase * PIX + o;
                            Pout[r0]           = NC[r0] * s;
                            Pout[r0 + PIX]     = NC[r0 + PIX] * s;
                            Pout[r0 + 2 * PIX] = NC[r0 + 2 * PIX] * s;
                            Pout[r0 + 3 * PIX] = NC[r0 + 3 * PIX] * s;
                        }
                    }
                }
}

// Phase A-a: [0,256) NC = notmF @ Mn^T, [256,320) En = emptyF @ Mem^T
__global__ void __launch_bounds__(512, 2) gemm8_faA(
    const f16* __restrict__ Mn, const f16* __restrict__ Mem,
    const f16* __restrict__ notmF, const f16* __restrict__ emptyF,
    f16* __restrict__ NC, f16* __restrict__ En) {
    __shared__ __attribute__((aligned(16))) char smem[131072];
    int bi = blockIdx.x;
    if (bi < 256) {
        gemm8_run<0>(bi, 8, smem, notmF, Mn, nullptr, nullptr, nullptr,
                     nullptr, nullptr, NC, PIX);
    } else {
        gemm8_run<0>(bi - 256, 2, smem, emptyF, Mem, nullptr, nullptr, nullptr,
                     nullptr, nullptr, En, PIX);
    }
}

// Phase A-b: stage1 GEMM (eachF @ Me^T) with fused mk_sa -> Lsel, P1
__global__ void __launch_bounds__(512, 2) gemm8_faB(
    const f16* __restrict__ Me, const f16* __restrict__ eachF,
    const unsigned char* __restrict__ board, const f16* __restrict__ En,
    const f16* __restrict__ NC, f16* __restrict__ Lsel, f16* __restrict__ P1) {
    __shared__ __attribute__((aligned(16))) char smem[131072];
    gemm8_run<2>(blockIdx.x, 8, smem, eachF, Me, board, En, NC, Lsel, P1,
                 nullptr, 0);
}

// Depth: Pin @ Mn2^T; MODE 3 emits Lsel + Pout, MODE 4 emits feat
template <int MODE>
__global__ void __launch_bounds__(512, 2) gemm8_depth(
    const f16* __restrict__ Pin, const f16* __restrict__ Mn2,
    const unsigned char* __restrict__ board, const f16* __restrict__ En,
    const f16* __restrict__ NC, f16* __restrict__ Lsel,
    f16* __restrict__ Pout, f16* __restrict__ feat) {
    __shared__ __attribute__((aligned(16))) char smem[131072];
    gemm8_run<MODE>(blockIdx.x, 8, smem, Pin, Mn2, board, En, NC, Lsel, Pout,
                    feat, 0);
}

// ---------------------------------------------------------------------------
// MLP: X1 = leaky(feat @ W1b^T) per 128-batch block, layers 2+3 fused (as-is)
// ---------------------------------------------------------------------------
__global__ void __launch_bounds__(256) gemm_mlp_fused(
    const f16* __restrict__ feat, const f16* __restrict__ W1b,
    const float* __restrict__ W2, const float* __restrict__ W3,
    float* __restrict__ out) {
    __shared__ __attribute__((aligned(16))) char smem[47360];
    char* smB = smem;
    char* smA = smem + 16384;

    const int tid = threadIdx.x;
    const int wv = tid >> 6, ln = tid & 63;
    const int wm = wv >> 1, wn_ = wv & 1;
    const int lr = ln & 15, lq = ln >> 4;
    const int rtile = blockIdx.x * 128;

    const f32x4 fz = {0.f, 0.f, 0.f, 0.f};
    f32x4 acc[4][4];
#pragma unroll
    for (int i = 0; i < 4; i++)
#pragma unroll
        for (int j = 0; j < 4; j++) acc[i][j] = fz;

    for (int kb = 0; kb < 1024; kb += 64) {
#pragma unroll
        for (int t = 0; t < 4; t++) {
            int c = (wv * 4 + t) * 64 + ln;
            int row = c >> 3, gcol = (c & 7) ^ (row & 7);
            gld_lds16(W1b  + (size_t)row * 1024 + kb + gcol * 8, smB + c * 16);
            gld_lds16(feat + (size_t)(rtile + row) * 1024 + kb + gcol * 8, smA + c * 16);
        }
        __syncthreads();
#pragma unroll
        for (int kk = 0; kk < 2; kk++) {
            const int oct = kk * 4 + lq;
            f16x8 af[4], bfr[4];
#pragma unroll
            for (int i = 0; i < 4; i++) {
                int rrow = wm * 64 + i * 16 + lr;
                af[i] = *(const f16x8*)(smA + rrow * 128 + (oct ^ (rrow & 7)) * 16);
            }
#pragma unroll
            for (int j = 0; j < 4; j++) {
                int brow = wn_ * 64 + j * 16 + lr;
                bfr[j] = *(const f16x8*)(smB + brow * 128 + (oct ^ (brow & 7)) * 16);
            }
#pragma unroll
            for (int i = 0; i < 4; i++)
#pragma unroll
                for (int j = 0; j < 4; j++)
                    acc[i][j] = __builtin_amdgcn_mfma_f32_16x16x32_f16(
                        af[i], bfr[j], acc[i][j], 0, 0, 0);
        }
        __syncthreads();
    }

    float* xs  = (float*)smem;                     // [64][101]
    f16*   sW2 = (f16*)(smem + 25856);             // [100][100]
    float* sW3 = (float*)(smem + 45856);           // [100]
    float* red = (float*)(smem + 46272);           // [256]
    for (int idx = tid; idx < 10000; idx += 256) sW2[idx] = (f16)W2[idx];
    if (tid < 100) sW3[tid] = W3[tid];

    for (int half = 0; half < 2; half++) {
        if (wm == half) {
#pragma unroll
            for (int i = 0; i < 4; i++) {
                int rb = i * 16 + lq * 4;
#pragma unroll
                for (int j = 0; j < 4; j++) {
                    int o = wn_ * 64 + j * 16 + lr;
                    if (o < 100) {
                        f32x4 a = acc[i][j];
#pragma unroll
                        for (int v = 0; v < 4; v++) {
                            float x = a[v];
                            xs[(rb + v) * 101 + o] = x > 0.f ? x : 0.2f * x;
                        }
                    }
                }
            }
        }
        __syncthreads();
        int nb = tid >> 2, q = tid & 3;
        const float* xrow = xs + nb * 101;
        float partial = 0.f;
        for (int jj = 0; jj < 25; jj++) {
            int j = q + jj * 4;
            const f16* w2r = sW2 + j * 100;
            float a2 = 0.f;
#pragma unroll
            for (int i = 0; i < 100; i++) a2 += (float)w2r[i] * xrow[i];
            partial += sW3[j] * (a2 > 0.f ? a2 : 0.2f * a2);
        }
        red[tid] = partial;
        __syncthreads();
        if (q == 0)
            out[rtile + half * 64 + nb] = red[tid] + red[tid + 1] + red[tid + 2] + red[tid + 3];
        __syncthreads();
    }
}

extern "C" void kernel_launch(void* const* d_in, const int* in_sizes, int n_in,
                              void* d_out, int out_size, void* d_ws, size_t ws_size,
                              hipStream_t stream) {
    (void)in_sizes; (void)n_in; (void)out_size; (void)ws_size;
    const int*   dots   = (const int*)d_in[0];
    const float* w_each = (const float*)d_in[1];
    const float* w_not  = (const float*)d_in[2];
    const float* w_not2 = (const float*)d_in[3];
    const float* w_emp  = (const float*)d_in[4];
    const float* W1 = (const float*)d_in[5];
    const float* W2 = (const float*)d_in[6];
    const float* W3 = (const float*)d_in[7];
    float* out = (float*)d_out;

    char* ws = (char*)d_ws;
    size_t off = 0;
    auto alloc = [&](size_t bytes) -> char* {
        char* p = ws + off;
        off += (bytes + 255) & ~(size_t)255;
        return p;
    };
    f16* Me    = (f16*)alloc((size_t)PIX * PIX * 2);
    f16* Mn    = (f16*)alloc((size_t)PIX * PIX * 2);
    f16* Mn2   = (f16*)alloc((size_t)PIX * PIX * 2);
    f16* Mem   = (f16*)alloc((size_t)PIX * PIX * 2);
    f16* W1b   = (f16*)alloc((size_t)128 * PIX * 2);
    unsigned char* board = (unsigned char*)alloc((size_t)NB * PIX);
    f16* eachF = (f16*)alloc((size_t)MR * PIX * 2);   // 32 MB, dead after faB
    f16* notmF = (f16*)alloc((size_t)MR * PIX * 2);   // 32 MB, dead after faA
    f16* emptyF= (f16*)alloc((size_t)NB * PIX * 2);   // 8 MB
    f16* NC    = (f16*)alloc((size_t)MR * PIX * 2);   // 32 MB
    f16* En    = (f16*)alloc((size_t)NB * PIX * 2);
    f16* Lsel  = (f16*)alloc((size_t)NB * PIX * 2);
    f16* feat  = (f16*)alloc((size_t)NB * PIX * 2);
    // P ping-pong buffers alias dead mask regions (32 MB each)
    f16* Pa = notmF;   // written by faB (notmF dead after faA)
    f16* Pb = eachF;   // written by depth1 (eachF dead after faB)

    dim3 blk(256), blk8(512);
    build_all<<<5632, blk, 0, stream>>>(w_each, w_not, w_not2, w_emp, W1, dots,
                                        Me, Mn, Mn2, Mem, W1b, board);
    expand_masks<<<10240, blk, 0, stream>>>(board, eachF, notmF, emptyF);
    // Phase A-a: NC + En
    gemm8_faA<<<320, blk8, 0, stream>>>(Mn, Mem, notmF, emptyF, NC, En);
    // Phase A-b: stage1 with fused mk_sa -> Lsel, P1 (into Pa)
    gemm8_faB<<<256, blk8, 0, stream>>>(Me, eachF, board, En, NC, Lsel, Pa);
    // depth 1..3: epilogue emits P_{d+1}
    gemm8_depth<3><<<256, blk8, 0, stream>>>(Pa, Mn2, board, En, NC, Lsel, Pb, nullptr);
    gemm8_depth<3><<<256, blk8, 0, stream>>>(Pb, Mn2, board, En, NC, Lsel, Pa, nullptr);
    gemm8_depth<3><<<256, blk8, 0, stream>>>(Pa, Mn2, board, En, NC, Lsel, Pb, nullptr);
    // depth 4 -> feat
    gemm8_depth<4><<<256, blk8, 0, stream>>>(Pb, Mn2, board, En, NC, Lsel, nullptr, feat);
    // MLP 1+2+3 fused
    gemm_mlp_fused<<<32, blk, 0, stream>>>(feat, W1b, W2, W3, out);
}